// Round 3
// baseline (190.886 us; speedup 1.0000x reference)
//
#include <hip/hip_runtime.h>
#include <math.h>

#define EPS  1e-6f
#define DD   256
#define NSUP 5
#define NQ   8
#define SEQ  13
#define L2E  1.44269504088896f
#define LN2  0.693147180559945f
#define NEP  2048            // episodes
#define NROW 16384           // NEP * NQ query rows
#define NCOL 2048            // anchor columns

typedef short bf16x8 __attribute__((ext_vector_type(8)));
typedef float f32x4  __attribute__((ext_vector_type(4)));

__device__ __forceinline__ ushort f2bf(float f) {
  union { float f; unsigned u; } v; v.f = f;
  unsigned r = v.u + 0x7FFFu + ((v.u >> 16) & 1u);   // round-to-nearest-even
  return (ushort)(r >> 16);
}
__device__ __forceinline__ float bf2f(short u) {
  union { unsigned u; float f; } v; v.u = ((unsigned)(unsigned short)u) << 16;
  return v.f;
}

// ---------------------------------------------------------------------------
// prep: bf16 anchors (mean of 5 supports) + bf16 queries + ca + zero accum.
//   ca[n] = sum(a^2) - 2*eps*sum(a)
// Shifted logit u = 2*dot(q,a) - ca  (row-constant cq cancels in loss; argmax
// unaffected). cq is not needed anywhere.
// ---------------------------------------------------------------------------
__global__ __launch_bounds__(256) void proto_prep(
    const float* __restrict__ x, float* __restrict__ ca,
    ushort* __restrict__ Abf, ushort* __restrict__ Qbf,
    float* __restrict__ accum, int* __restrict__ counter) {
  const int n = blockIdx.x, d = threadIdx.x;
  if (n == 0 && d == 0) { accum[0] = 0.f; accum[1] = 0.f; counter[0] = 0; }
  const float* xr = x + (size_t)n * SEQ * DD;

  float a = 0.f;
  #pragma unroll
  for (int s = 0; s < NSUP; ++s) a += xr[s * DD + d];
  a *= 0.2f;
  Abf[(size_t)n * DD + d] = f2bf(a);

  float s1 = a, s2 = a * a;
  #pragma unroll
  for (int off = 32; off; off >>= 1) {
    s1 += __shfl_xor(s1, off);
    s2 += __shfl_xor(s2, off);
  }
  __shared__ float red[8];
  const int wid = d >> 6, lane = d & 63;
  if (lane == 0) { red[wid] = s1; red[wid + 4] = s2; }
  __syncthreads();
  if (d == 0) {
    float t1 = red[0] + red[1] + red[2] + red[3];
    float t2 = red[4] + red[5] + red[6] + red[7];
    ca[n] = t2 - 2.f * EPS * t1;
  }
  #pragma unroll
  for (int s = 0; s < NQ; ++s)
    Qbf[((size_t)n * NQ + s) * DD + d] = f2bf(xr[(NSUP + s) * DD + d]);
}

// ---------------------------------------------------------------------------
// main: bf16 MFMA cross-GEMM fused with online max/sumexp/argmax in the
// log2-shifted frame v2 = (2*cross - ca) * log2(e).
// Grid 1024: block b -> rows [(b>>1)*32, +32), col-half (b&1) of 1024 cols.
// 4 waves/block, wave w -> 256-col stripe (16 tiles), 2 row-sets of 16 share
// every B fragment (2 MFMAs per B load). One-exp online update per C slot.
// Per-row partials (m2, s, argmax) written to global; merged by proto_merge.
// MFMA layouts (verified): A m=lane&15,k=quad*8+j ; B n=lane&15,k=quad*8+j ;
// C col=lane&15,row=quad*4+reg.
// ---------------------------------------------------------------------------
__global__ __launch_bounds__(256, 3) void proto_main(
    const ushort* __restrict__ Qbf, const ushort* __restrict__ Abf,
    const float* __restrict__ ca,
    float* __restrict__ pm, float* __restrict__ ps, int* __restrict__ pb) {
  const int tid   = threadIdx.x;
  const int wid   = tid >> 6, lane = tid & 63;
  const int quad  = lane >> 4, lcol = lane & 15;
  const int r0    = (blockIdx.x >> 1) * 32;
  const int chalf = blockIdx.x & 1;
  const int col0  = chalf * (NCOL / 2) + wid * (NCOL / 8);

  // resident A fragments: 2 row-sets x 8 K-chunks
  bf16x8 af[2][8];
  #pragma unroll
  for (int set = 0; set < 2; ++set) {
    const ushort* qp = Qbf + (size_t)(r0 + set * 16 + lcol) * DD + quad * 8;
    #pragma unroll
    for (int kk = 0; kk < 8; ++kk) af[set][kk] = *(const bf16x8*)(qp + kk * 32);
  }

  float m[2][4], s[2][4];
  int   bi[2][4];
  #pragma unroll
  for (int set = 0; set < 2; ++set)
    #pragma unroll
    for (int i = 0; i < 4; ++i) {
      m[set][i] = -1e30f; s[set][i] = 0.f; bi[set][i] = 0x7fffffff;
    }

  #pragma unroll 1
  for (int t = 0; t < 16; ++t) {
    const int colIdx = col0 + t * 16 + lcol;
    const ushort* bp = Abf + (size_t)colIdx * DD + quad * 8;
    f32x4 c0 = {0.f, 0.f, 0.f, 0.f}, c1 = {0.f, 0.f, 0.f, 0.f};
    #pragma unroll
    for (int kk = 0; kk < 8; ++kk) {
      bf16x8 b = *(const bf16x8*)(bp + kk * 32);
      c0 = __builtin_amdgcn_mfma_f32_16x16x32_bf16(af[0][kk], b, c0, 0, 0, 0);
      c1 = __builtin_amdgcn_mfma_f32_16x16x32_bf16(af[1][kk], b, c1, 0, 0, 0);
    }
    const float na = ca[colIdx] * (-L2E);
    #pragma unroll
    for (int set = 0; set < 2; ++set) {
      #pragma unroll
      for (int i = 0; i < 4; ++i) {
        float cv = (set == 0) ? c0[i] : c1[i];
        float v2 = fmaf(cv, 2.f * L2E, na);
        float d  = v2 - m[set][i];
        bool  gt = d > 0.f;
        float e  = exp2f(-fabsf(d));          // the non-unit exp factor
        float mf = gt ? e : 1.f;
        float ad = gt ? 1.f : e;
        s[set][i]  = fmaf(s[set][i], mf, ad);
        m[set][i]  = gt ? v2 : m[set][i];
        bi[set][i] = gt ? colIdx : bi[set][i];  // strict >: first max wins
      }
    }
  }

  // merge across the 16 lanes sharing rows (cols differ)
  #pragma unroll
  for (int mask = 1; mask < 16; mask <<= 1) {
    #pragma unroll
    for (int set = 0; set < 2; ++set)
      #pragma unroll
      for (int i = 0; i < 4; ++i) {
        float om = __shfl_xor(m[set][i], mask);
        float os = __shfl_xor(s[set][i], mask);
        int   oi = __shfl_xor(bi[set][i], mask);
        float nm = fmaxf(m[set][i], om);
        s[set][i] = s[set][i] * exp2f(m[set][i] - nm) + os * exp2f(om - nm);
        bool better = (om > m[set][i]) || (om == m[set][i] && oi < bi[set][i]);
        bi[set][i] = better ? oi : bi[set][i];
        m[set][i]  = nm;
      }
  }

  __shared__ float sm[4][32], ssh[4][32];
  __shared__ int   sbi[4][32];
  if (lcol == 0) {
    #pragma unroll
    for (int set = 0; set < 2; ++set)
      #pragma unroll
      for (int i = 0; i < 4; ++i) {
        int rl = set * 16 + quad * 4 + i;
        sm[wid][rl] = m[set][i]; ssh[wid][rl] = s[set][i]; sbi[wid][rl] = bi[set][i];
      }
  }
  __syncthreads();
  if (tid < 32) {
    float mm = sm[0][tid], sv = ssh[0][tid];
    int   b  = sbi[0][tid];
    #pragma unroll
    for (int w = 1; w < 4; ++w) {            // stripes in ascending col order
      float om = sm[w][tid], os = ssh[w][tid];
      int   oi = sbi[w][tid];
      float nm = fmaxf(mm, om);
      sv = sv * exp2f(mm - nm) + os * exp2f(om - nm);
      bool better = (om > mm) || (om == mm && oi < b);
      b = better ? oi : b;
      mm = nm;
    }
    const int row = r0 + tid;
    pm[chalf * NROW + row] = mm;
    ps[chalf * NROW + row] = sv;
    pb[chalf * NROW + row] = b;
  }
}

// ---------------------------------------------------------------------------
// merge: per row, combine the two col-half partials, add the label logit
// (direct bf16 dot, 16 lanes/row), reduce loss/precision, finalize in the
// last block via completion counter.
//   loss_row = ln2*m2 + ln(s) - (2*dot(q,a_lab) - ca[lab])
// ---------------------------------------------------------------------------
__global__ __launch_bounds__(256) void proto_merge(
    const ushort* __restrict__ Qbf, const ushort* __restrict__ Abf,
    const float* __restrict__ ca, const int* __restrict__ label,
    const float* __restrict__ pm, const float* __restrict__ ps,
    const int* __restrict__ pb,
    float* __restrict__ accum, int* __restrict__ counter,
    float* __restrict__ out) {
  const int tid = threadIdx.x, wid = tid >> 6, lane = tid & 63;
  const int grp = lane >> 4, lcol = lane & 15;
  const int row = blockIdx.x * 16 + wid * 4 + grp;
  const int lab = label[row >> 3];

  const ushort* qp = Qbf + (size_t)row * DD + lcol * 16;
  const ushort* ap = Abf + (size_t)lab * DD + lcol * 16;
  bf16x8 q0 = *(const bf16x8*)(qp),     q1 = *(const bf16x8*)(qp + 8);
  bf16x8 a0 = *(const bf16x8*)(ap),     a1 = *(const bf16x8*)(ap + 8);
  float dot = 0.f;
  #pragma unroll
  for (int i = 0; i < 8; ++i) {
    dot = fmaf(bf2f(q0[i]), bf2f(a0[i]), dot);
    dot = fmaf(bf2f(q1[i]), bf2f(a1[i]), dot);
  }
  #pragma unroll
  for (int mask = 1; mask < 16; mask <<= 1) dot += __shfl_xor(dot, mask);

  __shared__ float lred[2][16];
  if (lcol == 0) {
    float ma = pm[row],        mb = pm[NROW + row];
    float sa = ps[row],        sb = ps[NROW + row];
    int   ba = pb[row],        bb = pb[NROW + row];
    float nm = fmaxf(ma, mb);
    float sv = sa * exp2f(ma - nm) + sb * exp2f(mb - nm);
    bool better = (mb > ma) || (mb == ma && bb < ba);
    int  bidx = better ? bb : ba;
    float ulab = fmaf(2.f, dot, -ca[lab]);
    float loss = LN2 * nm + logf(sv) - ulab;
    float corr = (bidx == lab) ? 1.f : 0.f;
    lred[0][wid * 4 + grp] = loss;
    lred[1][wid * 4 + grp] = corr;
  }
  __syncthreads();
  if (tid == 0) {
    float L = 0.f, C = 0.f;
    #pragma unroll
    for (int i = 0; i < 16; ++i) { L += lred[0][i]; C += lred[1][i]; }
    atomicAdd(&accum[0], L);
    atomicAdd(&accum[1], C);
    __threadfence();
    int old = atomicAdd(counter, 1);
    if (old == (int)gridDim.x - 1) {
      float a0v = atomicAdd(&accum[0], 0.f);   // coherent device-scope read
      float a1v = atomicAdd(&accum[1], 0.f);
      out[0] = a0v / (float)NROW;
      out[1] = a1v * 100.f / (float)NROW;
    }
  }
}

// ---------------------------------------------------------------------------
extern "C" void kernel_launch(void* const* d_in, const int* in_sizes, int n_in,
                              void* d_out, int out_size, void* d_ws, size_t ws_size,
                              hipStream_t stream) {
  const float* x     = (const float*)d_in[0];
  const int*   label = (const int*)d_in[1];
  float* out = (float*)d_out;

  // ws layout (floats):
  // [0:2) accum | [2] counter | [16,16+NEP) ca | pm[2*NROW] | ps[2*NROW] |
  // pb[2*NROW] (int) | Abf (NEP*DD bf16) | Qbf (NROW*DD bf16)
  float*  W       = (float*)d_ws;
  float*  accum   = W;
  int*    counter = (int*)(W + 2);
  float*  ca      = W + 16;
  float*  pm      = ca + NEP;
  float*  ps      = pm + 2 * NROW;
  int*    pb      = (int*)(ps + 2 * NROW);
  ushort* Abf     = (ushort*)(pb + 2 * NROW);
  ushort* Qbf     = Abf + (size_t)NEP * DD;

  hipLaunchKernelGGL(proto_prep, dim3(NEP), dim3(256), 0, stream,
                     x, ca, Abf, Qbf, accum, counter);
  hipLaunchKernelGGL(proto_main, dim3(NROW / 32 * 2), dim3(256), 0, stream,
                     Qbf, Abf, ca, pm, ps, pb);
  hipLaunchKernelGGL(proto_merge, dim3(NROW / 16), dim3(256), 0, stream,
                     Qbf, Abf, ca, label, pm, ps, pb, accum, counter, out);
}

// Round 4
// 124.497 us; speedup vs baseline: 1.5333x; 1.5333x over previous
//
#include <hip/hip_runtime.h>
#include <math.h>

#define EPS  1e-6f
#define DD   256
#define NSUP 5
#define NQ   8
#define SEQ  13
#define L2E  1.44269504088896f
#define LN2  0.693147180559945f
#define NEP  2048            // episodes
#define NROW 16384           // NEP*NQ query rows
#define NCOL 2048            // anchor columns

typedef short bf16x8 __attribute__((ext_vector_type(8)));
typedef float f32x4  __attribute__((ext_vector_type(4)));

__device__ __forceinline__ ushort f2bf(float f) {
  union { float f; unsigned u; } v; v.f = f;
  unsigned r = v.u + 0x7FFFu + ((v.u >> 16) & 1u);   // round-to-nearest-even
  return (ushort)(r >> 16);
}

// ---------------------------------------------------------------------------
// prep: write anchors/queries directly in MFMA-fragment-SWIZZLED order so the
// main kernel's fragment loads are perfectly coalesced (lane*16B contiguous).
// Swizzle for element (c, d) [c = col or row]:
//   T=c>>4, lc=c&15, kk=d>>5, quad=(d>>3)&3, j=d&7
//   ushort index = ((T*8+kk)*64 + quad*16 + lc)*8 + j
// Main then loads fragment chunk kk of block T at byte addr (T*8+kk)*1024 +
// lane*16 — one fully-coalesced dwordx4 per chunk.
// Also: cb[c] = -log2(e) * (sum(a^2) - 2*eps*sum(a))  (row-constant cq
// cancels in the loss; logits handled in the log2-shifted frame).
// ---------------------------------------------------------------------------
__global__ __launch_bounds__(256) void proto_prep(
    const float* __restrict__ x, float* __restrict__ cb,
    ushort* __restrict__ Asw, ushort* __restrict__ Qsw,
    float* __restrict__ accum, int* __restrict__ counter) {
  const int n = blockIdx.x, d = threadIdx.x;
  if (n == 0 && d == 0) { accum[0] = 0.f; accum[1] = 0.f; counter[0] = 0; }
  const float* xr = x + (size_t)n * SEQ * DD;

  const int kk = d >> 5, quad = (d >> 3) & 3, j = d & 7;
  const size_t dpart = (size_t)kk * 64 + quad * 16;   // within-T part from d

  float a = 0.f;
  #pragma unroll
  for (int s = 0; s < NSUP; ++s) a += xr[s * DD + d];
  a *= 0.2f;
  Asw[(((size_t)(n >> 4) * 8 * 64) + dpart + (n & 15)) * 8 + j] = f2bf(a);

  float s1 = a, s2 = a * a;
  #pragma unroll
  for (int off = 32; off; off >>= 1) {
    s1 += __shfl_xor(s1, off);
    s2 += __shfl_xor(s2, off);
  }
  __shared__ float red[8];
  const int wid = d >> 6, lane = d & 63;
  if (lane == 0) { red[wid] = s1; red[wid + 4] = s2; }
  __syncthreads();
  if (d == 0) {
    float t1 = red[0] + red[1] + red[2] + red[3];
    float t2 = red[4] + red[5] + red[6] + red[7];
    cb[n] = -L2E * (t2 - 2.f * EPS * t1);
  }
  #pragma unroll
  for (int s = 0; s < NQ; ++s) {
    const int row = n * NQ + s;
    Qsw[(((size_t)(row >> 4) * 8 * 64) + dpart + (row & 15)) * 8 + j]
        = f2bf(xr[(NSUP + s) * DD + d]);
  }
}

// ---------------------------------------------------------------------------
// main: bf16 MFMA cross-GEMM fused with online softmax/argmax, 512 blocks.
// Block = 32 rows; wave w owns col stripe [w*512, +512) = 32 col-tiles of 16.
// All fragment loads coalesced (swizzled layout). Register ping-pong prefetch
// of the next B tile overlaps loads with MFMA+epilogue. In-block reduction,
// one atomicAdd pair per block, completion-counter finalize (no extra
// kernels). MFMA layouts (verified): A m=lane&15,k=quad*8+j ; B n=lane&15,
// k=quad*8+j ; C col=lane&15,row=quad*4+reg.
// ---------------------------------------------------------------------------
__global__ __launch_bounds__(256, 2) void proto_main(
    const ushort* __restrict__ Qsw, const ushort* __restrict__ Asw,
    const float* __restrict__ cb, const int* __restrict__ label,
    float* __restrict__ accum, int* __restrict__ counter,
    float* __restrict__ out) {
  const int tid  = threadIdx.x;
  const int wid  = tid >> 6, lane = tid & 63;
  const int quad = lane >> 4, lcol = lane & 15;
  const int r0   = blockIdx.x * 32;

  const bf16x8* qb = (const bf16x8*)Qsw;
  const bf16x8* bb = (const bf16x8*)Asw;

  // resident A fragments: 2 row-sets x 8 K-chunks (coalesced loads)
  bf16x8 af[2][8];
  #pragma unroll
  for (int set = 0; set < 2; ++set) {
    const size_t base = ((size_t)((r0 >> 4) + set) * 8) * 64 + lane;
    #pragma unroll
    for (int kk = 0; kk < 8; ++kk) af[set][kk] = qb[base + (size_t)kk * 64];
  }

  float m[2][4], s[2][4], ll[2][4];
  int   bi[2][4], lab[2][4];
  #pragma unroll
  for (int set = 0; set < 2; ++set)
    #pragma unroll
    for (int i = 0; i < 4; ++i) {
      m[set][i] = -1e30f; s[set][i] = 0.f; ll[set][i] = 0.f;
      bi[set][i] = 0x7fffffff;
      lab[set][i] = label[(r0 + set * 16 + quad * 4 + i) >> 3];
    }

  auto process = [&](int T, bf16x8* B) {
    f32x4 c0 = {0.f, 0.f, 0.f, 0.f}, c1 = {0.f, 0.f, 0.f, 0.f};
    #pragma unroll
    for (int kk = 0; kk < 8; ++kk) {
      c0 = __builtin_amdgcn_mfma_f32_16x16x32_bf16(af[0][kk], B[kk], c0, 0, 0, 0);
      c1 = __builtin_amdgcn_mfma_f32_16x16x32_bf16(af[1][kk], B[kk], c1, 0, 0, 0);
    }
    const int   colIdx = T * 16 + lcol;
    const float cbv    = cb[colIdx];       // 64-B broadcast segment
    #pragma unroll
    for (int set = 0; set < 2; ++set) {
      #pragma unroll
      for (int i = 0; i < 4; ++i) {
        float cv = (set == 0) ? c0[i] : c1[i];
        float v2 = fmaf(cv, 2.f * L2E, cbv);     // log2-frame shifted logit
        float dv = v2 - m[set][i];
        bool  gt = dv > 0.f;
        float e  = exp2f(-fabsf(dv));            // the single non-unit factor
        s[set][i]  = fmaf(s[set][i], gt ? e : 1.f, gt ? 1.f : e);
        m[set][i]  = gt ? v2 : m[set][i];
        bi[set][i] = gt ? colIdx : bi[set][i];   // strict >: first max wins
        ll[set][i] = (colIdx == lab[set][i]) ? v2 : ll[set][i];
      }
    }
  };

  const int T0 = wid * 32;
  bf16x8 buf0[8], buf1[8];
  #pragma unroll
  for (int kk = 0; kk < 8; ++kk)
    buf0[kk] = bb[((size_t)T0 * 8 + (size_t)kk) * 64 + lane];

  #pragma unroll 1
  for (int t = 0; t < 32; t += 2) {
    {
      const int Tn = T0 + t + 1;                           // always valid
      #pragma unroll
      for (int kk = 0; kk < 8; ++kk)
        buf1[kk] = bb[((size_t)Tn * 8 + (size_t)kk) * 64 + lane];
    }
    process(T0 + t, buf0);
    {
      const int Tn = (t + 2 < 32) ? T0 + t + 2 : T0 + t + 1;  // clamp tail
      #pragma unroll
      for (int kk = 0; kk < 8; ++kk)
        buf0[kk] = bb[((size_t)Tn * 8 + (size_t)kk) * 64 + lane];
    }
    process(T0 + t + 1, buf1);
  }

  // merge across the 16 lanes sharing rows (cols differ)
  #pragma unroll
  for (int mask = 1; mask < 16; mask <<= 1) {
    #pragma unroll
    for (int set = 0; set < 2; ++set)
      #pragma unroll
      for (int i = 0; i < 4; ++i) {
        float om = __shfl_xor(m[set][i], mask);
        float os = __shfl_xor(s[set][i], mask);
        int   oi = __shfl_xor(bi[set][i], mask);
        float ol = __shfl_xor(ll[set][i], mask);
        float nm = fmaxf(m[set][i], om);
        s[set][i] = s[set][i] * exp2f(m[set][i] - nm) + os * exp2f(om - nm);
        bool better = (om > m[set][i]) || (om == m[set][i] && oi < bi[set][i]);
        bi[set][i] = better ? oi : bi[set][i];
        m[set][i]  = nm;
        ll[set][i] += ol;       // exactly one slot holds the label logit
      }
  }

  __shared__ float sm[4][32], ssh[4][32], sll[4][32];
  __shared__ int   sbi[4][32];
  if (lcol == 0) {
    #pragma unroll
    for (int set = 0; set < 2; ++set)
      #pragma unroll
      for (int i = 0; i < 4; ++i) {
        int rl = set * 16 + quad * 4 + i;
        sm[wid][rl] = m[set][i];  ssh[wid][rl] = s[set][i];
        sll[wid][rl] = ll[set][i]; sbi[wid][rl] = bi[set][i];
      }
  }
  __syncthreads();
  if (tid < 32) {
    float mm = sm[0][tid], sv = ssh[0][tid], lv = sll[0][tid];
    int   b  = sbi[0][tid];
    #pragma unroll
    for (int w = 1; w < 4; ++w) {            // stripes in ascending col order
      float om = sm[w][tid], os = ssh[w][tid];
      int   oi = sbi[w][tid];
      float nm = fmaxf(mm, om);
      sv = sv * exp2f(mm - nm) + os * exp2f(om - nm);
      bool better = (om > mm) || (om == mm && oi < b);
      b = better ? oi : b;
      mm = nm;
      lv += sll[w][tid];
    }
    const int row = r0 + tid;
    const int lb  = label[row >> 3];
    float loss = LN2 * (mm + log2f(sv) - lv);
    float corr = (b == lb) ? 1.f : 0.f;
    #pragma unroll
    for (int mask = 16; mask; mask >>= 1) {
      loss += __shfl_xor(loss, mask);
      corr += __shfl_xor(corr, mask);
    }
    if (tid == 0) {
      atomicAdd(&accum[0], loss);
      atomicAdd(&accum[1], corr);
      __threadfence();
      if (atomicAdd(counter, 1) == (int)gridDim.x - 1) {
        out[0] = atomicAdd(&accum[0], 0.f) / (float)NROW;   // coherent reads
        out[1] = atomicAdd(&accum[1], 0.f) * 100.f / (float)NROW;
      }
    }
  }
}

// ---------------------------------------------------------------------------
extern "C" void kernel_launch(void* const* d_in, const int* in_sizes, int n_in,
                              void* d_out, int out_size, void* d_ws, size_t ws_size,
                              hipStream_t stream) {
  const float* x     = (const float*)d_in[0];
  const int*   label = (const int*)d_in[1];
  float* out = (float*)d_out;

  // ws layout (floats): [0:2) accum | [2] counter | [16,16+NCOL) cb |
  //                     Asw (NCOL*DD ushort) | Qsw (NROW*DD ushort)
  float*  W       = (float*)d_ws;
  float*  accum   = W;
  int*    counter = (int*)(W + 2);
  float*  cb      = W + 16;
  ushort* Asw     = (ushort*)(cb + NCOL);
  ushort* Qsw     = Asw + (size_t)NCOL * DD;

  hipLaunchKernelGGL(proto_prep, dim3(NEP), dim3(256), 0, stream,
                     x, cb, Asw, Qsw, accum, counter);
  hipLaunchKernelGGL(proto_main, dim3(NROW / 32), dim3(256), 0, stream,
                     Qsw, Asw, cb, label, accum, counter, out);
}